// Round 5
// baseline (78.619 us; speedup 1.0000x reference)
//
#include <hip/hip_runtime.h>
#include <math.h>

// MoE router: x [16384, 2048] f32, gate_w [8, 2048] f32
// outputs (concatenated f32): weights [16384,2] | mask [8,2,16384] | logits [16384,8]

constexpr int kN = 16384;
constexpr int kD = 2048;
constexpr int kE = 8;

using f4 = __attribute__((ext_vector_type(4))) float;

__global__ __launch_bounds__(256, 4)
void moe_router_kernel(const float* __restrict__ x,
                       const float* __restrict__ gw,
                       float* __restrict__ out)
{
    const int lane = threadIdx.x & 63;
    const int wv   = threadIdx.x >> 6;
    const int n0   = blockIdx.x * 16 + wv * 4;   // 4 rows per wave

    const float* xr = x + (long)n0 * kD;

    float acc[4][8];
#pragma unroll
    for (int r = 0; r < 4; ++r)
#pragma unroll
        for (int e = 0; e < 8; ++e) acc[r][e] = 0.f;

    // Ping-pong x prefetch. Issue order per half-iteration:
    //   [ gate loads (L2) ] then [ next-chunk x loads (HBM, NT) ] then FMAs.
    // FMAs wait vmcnt(4) -> the 4 x-loads stay in flight across the FMA
    // block and the next half's gate-wait. 8 KB x in flight per wave
    // (vs 4 KB with a drain-every-iter loop) -> 128 KB/CU -> HBM-saturating.
    f4 xA[4], xB[4];
#pragma unroll
    for (int r = 0; r < 4; ++r)
        xA[r] = __builtin_nontemporal_load(
            reinterpret_cast<const f4*>(xr + (long)r * kD + lane * 4));

#pragma unroll 1
    for (int it = 0; it < 8; it += 2) {
        // ---- even half: consume xA, prefetch xB for chunk it+1 ----
        {
            const int c = it * 256 + lane * 4;
            f4 g[8];
#pragma unroll
            for (int e = 0; e < 8; ++e)
                g[e] = *reinterpret_cast<const f4*>(gw + e * kD + c);
            const int cn = (it + 1) * 256 + lane * 4;
#pragma unroll
            for (int r = 0; r < 4; ++r)
                xB[r] = __builtin_nontemporal_load(
                    reinterpret_cast<const f4*>(xr + (long)r * kD + cn));
#pragma unroll
            for (int r = 0; r < 4; ++r)
#pragma unroll
                for (int e = 0; e < 8; ++e) {
                    acc[r][e] = fmaf(xA[r].x, g[e].x, acc[r][e]);
                    acc[r][e] = fmaf(xA[r].y, g[e].y, acc[r][e]);
                    acc[r][e] = fmaf(xA[r].z, g[e].z, acc[r][e]);
                    acc[r][e] = fmaf(xA[r].w, g[e].w, acc[r][e]);
                }
        }
        // ---- odd half: consume xB, prefetch xA for chunk it+2 ----
        {
            const int c = (it + 1) * 256 + lane * 4;
            f4 g[8];
#pragma unroll
            for (int e = 0; e < 8; ++e)
                g[e] = *reinterpret_cast<const f4*>(gw + e * kD + c);
            if (it < 6) {                    // uniform, cheap
                const int cn = (it + 2) * 256 + lane * 4;
#pragma unroll
                for (int r = 0; r < 4; ++r)
                    xA[r] = __builtin_nontemporal_load(
                        reinterpret_cast<const f4*>(xr + (long)r * kD + cn));
            }
#pragma unroll
            for (int r = 0; r < 4; ++r)
#pragma unroll
                for (int e = 0; e < 8; ++e) {
                    acc[r][e] = fmaf(xB[r].x, g[e].x, acc[r][e]);
                    acc[r][e] = fmaf(xB[r].y, g[e].y, acc[r][e]);
                    acc[r][e] = fmaf(xB[r].z, g[e].z, acc[r][e]);
                    acc[r][e] = fmaf(xB[r].w, g[e].w, acc[r][e]);
                }
        }
    }

    // ---- Fold-reduction: 56 shuffles. After this, every lane holds all 8
    // logits of row (lane&3), summed over all 64 lanes. ----
    const int rsel = lane & 1;
    float a2[2][8];
#pragma unroll
    for (int j = 0; j < 2; ++j)
#pragma unroll
        for (int e = 0; e < 8; ++e) {
            const float mine  = rsel ? acc[2 * j + 1][e] : acc[2 * j][e];
            const float other = rsel ? acc[2 * j][e]     : acc[2 * j + 1][e];
            a2[j][e] = mine + __shfl_xor(other, 1);
        }
    const int sel = (lane >> 1) & 1;
    float a1[8];
#pragma unroll
    for (int e = 0; e < 8; ++e) {
        const float mine  = sel ? a2[1][e] : a2[0][e];
        const float other = sel ? a2[0][e] : a2[1][e];
        a1[e] = mine + __shfl_xor(other, 2);
    }
#pragma unroll
    for (int e = 0; e < 8; ++e) {
        float v = a1[e];
        v += __shfl_xor(v, 4);
        v += __shfl_xor(v, 8);
        v += __shfl_xor(v, 16);
        v += __shfl_xor(v, 32);
        a1[e] = v;   // logit of (row = lane&3, expert = e)
    }

    // ---- per-lane top-2 (lowest-index tie-break) ----
    int s0 = 0; float b0 = a1[0];
#pragma unroll
    for (int e = 1; e < 8; ++e)
        if (a1[e] > b0) { b0 = a1[e]; s0 = e; }
    int s1 = 0; float b1 = -3.4e38f;
#pragma unroll
    for (int e = 0; e < 8; ++e) {
        const bool t = (e != s0) && (a1[e] > b1);
        b1 = t ? a1[e] : b1;
        s1 = t ? e : s1;
    }
    const float d  = expf(b1 - b0);          // <= 1
    const float w0 = 1.0f / (1.0f + d);      // p0/(p0+p1)
    const float w1 = d * w0;

    float* out_w = out;                            // [N, 2]
    float* out_m = out + 2 * kN;                   // [E, 2, N]
    float* out_l = out + 2 * kN + 2 * kE * kN;     // [N, 8]

    const int row = lane & 3;
    const int q   = lane >> 2;                     // 0..15

    // mask: lane = em*8 + km*4 + row (bijective over 8x2x4)
    {
        const int em = lane >> 3;
        const int km = (lane >> 2) & 1;
        const int ss = km ? s1 : s0;
        out_m[(long)em * (2 * kN) + (long)km * kN + (n0 + row)] =
            (ss == em) ? 1.0f : 0.0f;
    }
    // weights: lanes 0..7 -> (row = lane&3, k = lane>>2)
    if (lane < 8)
        out_w[(long)(n0 + row) * 2 + q] = q ? w1 : w0;
    // logits: lanes 0..31 -> (row = lane&3, e = lane>>2), 128B/row-group
    if (lane < 32) {
        float v = a1[0];
#pragma unroll
        for (int e = 1; e < 8; ++e)
            v = (q == e) ? a1[e] : v;
        out_l[(long)(n0 + row) * 8 + q] = v;
    }
}

extern "C" void kernel_launch(void* const* d_in, const int* in_sizes, int n_in,
                              void* d_out, int out_size, void* d_ws, size_t ws_size,
                              hipStream_t stream)
{
    (void)in_sizes; (void)n_in; (void)d_ws; (void)ws_size; (void)out_size;
    const float* x  = (const float*)d_in[0];
    const float* gw = (const float*)d_in[1];
    float* out = (float*)d_out;

    dim3 grid(kN / 16);   // 1024 blocks, 16 rows each, 4 blocks/CU
    dim3 block(256);
    moe_router_kernel<<<grid, block, 0, stream>>>(x, gw, out);
}

// Round 6
// 31.048 us; speedup vs baseline: 2.5322x; 2.5322x over previous
//
#include <hip/hip_runtime.h>
#include <math.h>

// MoE router: x [16384, 2048] f32, gate_w [8, 2048] f32
// outputs (concatenated f32): weights [16384,2] | mask [8,2,16384] | logits [16384,8]

constexpr int kN = 16384;
constexpr int kD = 2048;
constexpr int kE = 8;

using f4 = __attribute__((ext_vector_type(4))) float;

typedef const __attribute__((address_space(1))) uint32_t* gptr_t;
typedef __attribute__((address_space(3))) uint32_t* lptr_t;

__global__ __launch_bounds__(256, 4)
void moe_router_kernel(const float* __restrict__ x,
                       const float* __restrict__ gw,
                       float* __restrict__ out)
{
    // Wave-private x staging: [wave][pingpong][row][256 cols] = 32 KiB/block.
    // No __syncthreads anywhere -> no barrier vmcnt(0) drains.
    __shared__ float sx[4][2][4][256];

    const int lane = threadIdx.x & 63;
    const int wv   = threadIdx.x >> 6;
    const int n0   = blockIdx.x * 16 + wv * 4;   // 4 rows per wave

    const float* xr  = x + (long)n0 * kD;
    float*       sxw = &sx[wv][0][0][0];         // 2048 floats, wave-private

    float acc[4][8];
#pragma unroll
    for (int r = 0; r < 4; ++r)
#pragma unroll
        for (int e = 0; e < 8; ++e) acc[r][e] = 0.f;

    // Stage chunk `it` (4 rows x 1KB) into LDS buffer (it&1).
    // Global src is per-lane (c includes lane*4); LDS dst is wave-uniform,
    // HW writes lane l at dst + l*16 -> row-linear layout, matches reads.
    auto stage = [&](int it) {
        const int c = (it & 7) * 256 + lane * 4;
        float* dst = sxw + (it & 1) * 1024;
#pragma unroll
        for (int r = 0; r < 4; ++r)
            __builtin_amdgcn_global_load_lds(
                (gptr_t)(xr + (long)r * kD + c),
                (lptr_t)(dst + r * 256),
                16, 0, 0);
    };

    stage(0);   // prologue: 4 VMEM ops in flight

#pragma unroll 1
    for (int it = 0; it < 8; ++it) {
        const int c = it * 256 + lane * 4;
        // 1) gate loads (L2 -> VGPR), issued FIRST (older in vmcnt queue)
        f4 g[8];
#pragma unroll
        for (int e = 0; e < 8; ++e)
            g[e] = *reinterpret_cast<const f4*>(gw + e * kD + c);
        __builtin_amdgcn_sched_barrier(0);   // pin: gates before stages
        // 2) stage next chunk (it==7 re-stages chunk 0 into the dead buffer:
        //    keeps vmcnt(4) uniform; ~0.8% redundant traffic, mostly L3-hit)
        stage(it + 1);
        __builtin_amdgcn_sched_barrier(0);
        // 3) wait: gates + chunk-it stage done; next chunk's 4 stay in flight
        asm volatile("s_waitcnt vmcnt(4)" ::: "memory");
        __builtin_amdgcn_sched_barrier(0);
        // 4) read x chunk from LDS and accumulate
        const float* src = sxw + (it & 1) * 1024;
        f4 xv[4];
#pragma unroll
        for (int r = 0; r < 4; ++r)
            xv[r] = *reinterpret_cast<const f4*>(src + r * 256 + lane * 4);
#pragma unroll
        for (int r = 0; r < 4; ++r)
#pragma unroll
            for (int e = 0; e < 8; ++e) {
                acc[r][e] = fmaf(xv[r].x, g[e].x, acc[r][e]);
                acc[r][e] = fmaf(xv[r].y, g[e].y, acc[r][e]);
                acc[r][e] = fmaf(xv[r].z, g[e].z, acc[r][e]);
                acc[r][e] = fmaf(xv[r].w, g[e].w, acc[r][e]);
            }
    }

    // ---- Fold-reduction: 56 shuffles. After this, every lane holds all 8
    // logits of row (lane&3), summed over all 64 lanes. ----
    const int rsel = lane & 1;
    float a2[2][8];
#pragma unroll
    for (int j = 0; j < 2; ++j)
#pragma unroll
        for (int e = 0; e < 8; ++e) {
            const float mine  = rsel ? acc[2 * j + 1][e] : acc[2 * j][e];
            const float other = rsel ? acc[2 * j][e]     : acc[2 * j + 1][e];
            a2[j][e] = mine + __shfl_xor(other, 1);
        }
    const int sel = (lane >> 1) & 1;
    float a1[8];
#pragma unroll
    for (int e = 0; e < 8; ++e) {
        const float mine  = sel ? a2[1][e] : a2[0][e];
        const float other = sel ? a2[0][e] : a2[1][e];
        a1[e] = mine + __shfl_xor(other, 2);
    }
#pragma unroll
    for (int e = 0; e < 8; ++e) {
        float v = a1[e];
        v += __shfl_xor(v, 4);
        v += __shfl_xor(v, 8);
        v += __shfl_xor(v, 16);
        v += __shfl_xor(v, 32);
        a1[e] = v;   // logit of (row = lane&3, expert = e)
    }

    // ---- per-lane top-2 (lowest-index tie-break) ----
    int s0 = 0; float b0 = a1[0];
#pragma unroll
    for (int e = 1; e < 8; ++e)
        if (a1[e] > b0) { b0 = a1[e]; s0 = e; }
    int s1 = 0; float b1 = -3.4e38f;
#pragma unroll
    for (int e = 0; e < 8; ++e) {
        const bool t = (e != s0) && (a1[e] > b1);
        b1 = t ? a1[e] : b1;
        s1 = t ? e : s1;
    }
    const float d  = expf(b1 - b0);          // <= 1
    const float w0 = 1.0f / (1.0f + d);      // p0/(p0+p1)
    const float w1 = d * w0;

    float* out_w = out;                            // [N, 2]
    float* out_m = out + 2 * kN;                   // [E, 2, N]
    float* out_l = out + 2 * kN + 2 * kE * kN;     // [N, 8]

    const int row = lane & 3;
    const int q   = lane >> 2;                     // 0..15

    // mask: lane = em*8 + km*4 + row (bijective over 8x2x4)
    {
        const int em = lane >> 3;
        const int km = (lane >> 2) & 1;
        const int ss = km ? s1 : s0;
        out_m[(long)em * (2 * kN) + (long)km * kN + (n0 + row)] =
            (ss == em) ? 1.0f : 0.0f;
    }
    // weights: lanes 0..7 -> (row = lane&3, k = lane>>2)
    if (lane < 8)
        out_w[(long)(n0 + row) * 2 + q] = q ? w1 : w0;
    // logits: lanes 0..31 -> (row = lane&3, e = lane>>2), 128B/row-group
    if (lane < 32) {
        float v = a1[0];
#pragma unroll
        for (int e = 1; e < 8; ++e)
            v = (q == e) ? a1[e] : v;
        out_l[(long)(n0 + row) * 8 + q] = v;
    }
}

extern "C" void kernel_launch(void* const* d_in, const int* in_sizes, int n_in,
                              void* d_out, int out_size, void* d_ws, size_t ws_size,
                              hipStream_t stream)
{
    (void)in_sizes; (void)n_in; (void)d_ws; (void)ws_size; (void)out_size;
    const float* x  = (const float*)d_in[0];
    const float* gw = (const float*)d_in[1];
    float* out = (float*)d_out;

    dim3 grid(kN / 16);   // 1024 blocks, 16 rows each, 4 blocks/CU
    dim3 block(256);
    moe_router_kernel<<<grid, block, 0, stream>>>(x, gw, out);
}

// Round 7
// 30.448 us; speedup vs baseline: 2.5821x; 1.0197x over previous
//
#include <hip/hip_runtime.h>
#include <math.h>

// MoE router: x [16384, 2048] f32, gate_w [8, 2048] f32
// outputs (concatenated f32): weights [16384,2] | mask [8,2,16384] | logits [16384,8]
//
// Column-slice structure: 8 waves/block, wave wv owns cols [wv*256, wv*256+256).
// Gates held in 32 VGPRs (loaded once). Block reads rows fully contiguously
// (8 waves x 1KB = whole 8KB row), rows sequential -> fill-like DRAM pattern.
// Steady-state VMEM = 1 x-load per row per wave, prefetch distance 3.

constexpr int kN = 16384;
constexpr int kD = 2048;
constexpr int kE = 8;

using f4 = __attribute__((ext_vector_type(4))) float;

__global__ __launch_bounds__(512, 4)
void moe_router_kernel(const float* __restrict__ x,
                       const float* __restrict__ gw,
                       float* __restrict__ out)
{
    __shared__ float part[2][512];        // [buf][wv*64 + r*8 + e], 4 KiB

    const int tid  = threadIdx.x;
    const int lane = tid & 63;
    const int wv   = tid >> 6;                     // 0..7 column-slice owner
    const int col  = wv * 256 + lane * 4;          // this lane's 4 columns
    const int rowbase = blockIdx.x * 32;           // 32 rows per block

    const float* xc = x + col;

    // gate fragment, resident for the whole kernel (32 VGPRs)
    f4 g[8];
#pragma unroll
    for (int e = 0; e < 8; ++e)
        g[e] = *reinterpret_cast<const f4*>(gw + e * kD + col);

    float* out_w = out;                            // [N, 2]
    float* out_m = out + 2 * kN;                   // [E, 2, N]
    float* out_l = out + 2 * kN + 2 * kE * kN;     // [N, 8]

    // rolling x buffer: 4 slots, prefetch distance 3 (3 KB/wave in flight,
    // never drained: barriers below wait lgkmcnt only, not vmcnt)
    f4 xb[4];
#pragma unroll
    for (int p = 0; p < 3; ++p)
        xb[p] = __builtin_nontemporal_load(
            reinterpret_cast<const f4*>(xc + (long)(rowbase + p) * kD));

    float acc[8][8];
    const int b0 = lane & 1, b1 = (lane >> 1) & 1, b2 = (lane >> 2) & 1;

#pragma unroll 1
    for (int gidx = 0; gidx < 4; ++gidx) {
        const int r0 = rowbase + gidx * 8;

        // ---- 8 rows: 1 VMEM + 32 FMA each; acc[r][e] starts with a mul ----
#pragma unroll
        for (int r = 0; r < 8; ++r) {
            int prow = r0 + r + 3;                     // next prefetch row
            prow = prow > kN - 1 ? kN - 1 : prow;      // clamp (last block tail)
            xb[(r + 3) & 3] = __builtin_nontemporal_load(
                reinterpret_cast<const f4*>(xc + (long)prow * kD));
            const f4 xv = xb[r & 3];
#pragma unroll
            for (int e = 0; e < 8; ++e) {
                float t = xv.x * g[e].x;               // overwrites old acc
                t = fmaf(xv.y, g[e].y, t);
                t = fmaf(xv.z, g[e].z, t);
                acc[r][e] = fmaf(xv.w, g[e].w, t);
            }
        }

        // ---- in-place in-wave fold: 80 shuffles; afterwards acc[0][e] =
        // slice-partial logit of row r0+(lane&7), expert e ----
#pragma unroll
        for (int j = 0; j < 4; ++j)
#pragma unroll
            for (int e = 0; e < 8; ++e) {
                const float mine  = b0 ? acc[2 * j + 1][e] : acc[2 * j][e];
                const float other = b0 ? acc[2 * j][e]     : acc[2 * j + 1][e];
                acc[j][e] = mine + __shfl_xor(other, 1);
            }
#pragma unroll
        for (int k = 0; k < 2; ++k)
#pragma unroll
            for (int e = 0; e < 8; ++e) {
                const float mine  = b1 ? acc[2 * k + 1][e] : acc[2 * k][e];
                const float other = b1 ? acc[2 * k][e]     : acc[2 * k + 1][e];
                acc[k][e] = mine + __shfl_xor(other, 2);
            }
#pragma unroll
        for (int e = 0; e < 8; ++e) {
            const float mine  = b2 ? acc[1][e] : acc[0][e];
            const float other = b2 ? acc[0][e] : acc[1][e];
            float v = mine + __shfl_xor(other, 4);
            v += __shfl_xor(v, 8);
            v += __shfl_xor(v, 16);
            v += __shfl_xor(v, 32);
            acc[0][e] = v;
        }

        // ---- scatter this wave's partials: lane -> (r=lane&7, e=lane>>3) ----
        {
            const int er = lane >> 3;
            float v = acc[0][0];
#pragma unroll
            for (int e = 1; e < 8; ++e) v = (er == e) ? acc[0][e] : v;
            part[gidx & 1][wv * 64 + (lane & 7) * 8 + er] = v;
        }
        asm volatile("s_waitcnt lgkmcnt(0)" ::: "memory");
        __builtin_amdgcn_sched_barrier(0);
        __builtin_amdgcn_s_barrier();               // no vmcnt drain: x prefetch
        __builtin_amdgcn_sched_barrier(0);          // stays in flight

        // ---- epilogue (one wave per group, rotating): rows r0..r0+7 ----
        if (wv == gidx) {
            const int r = lane & 7, c = lane >> 3;  // lane -> (row, expert)
            const float* pb = &part[gidx & 1][0];
            float L = 0.f;
#pragma unroll
            for (int w = 0; w < 8; ++w)
                L += pb[w * 64 + r * 8 + c];        // logit[r0+r][c]

            float le[8];                            // gather row's 8 logits
#pragma unroll
            for (int e = 0; e < 8; ++e)
                le[e] = __shfl(L, r + 8 * e);

            int s0 = 0; float v0 = le[0];
#pragma unroll
            for (int e = 1; e < 8; ++e)
                if (le[e] > v0) { v0 = le[e]; s0 = e; }
            int s1 = 0; float v1 = -3.4e38f;
#pragma unroll
            for (int e = 0; e < 8; ++e) {
                const bool t = (e != s0) && (le[e] > v1);
                v1 = t ? le[e] : v1;
                s1 = t ? e : s1;
            }
            const float d  = expf(v1 - v0);         // <= 1
            const float w0 = 1.0f / (1.0f + d);     // p0/(p0+p1)
            const float w1 = d * w0;

            out_l[(long)(r0 + r) * 8 + c] = L;
            out_m[(long)c * (2 * kN) + (r0 + r)]      = (s0 == c) ? 1.0f : 0.0f;
            out_m[(long)c * (2 * kN) + kN + (r0 + r)] = (s1 == c) ? 1.0f : 0.0f;
            if (c == 0) {
                float2 wp; wp.x = w0; wp.y = w1;
                *reinterpret_cast<float2*>(out_w + (long)(r0 + r) * 2) = wp;
            }
        }
    }
}

extern "C" void kernel_launch(void* const* d_in, const int* in_sizes, int n_in,
                              void* d_out, int out_size, void* d_ws, size_t ws_size,
                              hipStream_t stream)
{
    (void)in_sizes; (void)n_in; (void)d_ws; (void)ws_size; (void)out_size;
    const float* x  = (const float*)d_in[0];
    const float* gw = (const float*)d_in[1];
    float* out = (float*)d_out;

    dim3 grid(kN / 32);   // 512 blocks x 32 rows; 2 blocks/CU
    dim3 block(512);      // 8 waves, one column slice each
    moe_router_kernel<<<grid, block, 0, stream>>>(x, gw, out);
}